// Round 4
// baseline (295.975 us; speedup 1.0000x reference)
//
#include <hip/hip_runtime.h>
#include <hip/hip_cooperative_groups.h>
#include <math.h>

namespace cg = cooperative_groups;

// ---------------------------------------------------------------------------
// TropicalMLP, single cooperative kernel (was 7 dispatches; launch gaps
// dominated). h_i = logsumexp_j(x_j + w_ij) + b_i = log(sum_j e^x_j e^w_ij)+b_i
// => layer = f16 MFMA GEMM on pre-exponentiated operands, log fused downstream.
// Per-row max subtracted before exp (uniform shift cancels exactly in the
// tropical-LN; added back in the final epilogue) => f16-safe range.
// Phases separated by grid.sync(): exp -> G1 -> LN1 -> G2 -> LN2 -> G3+epi.
// ---------------------------------------------------------------------------

typedef _Float16 v8h __attribute__((ext_vector_type(8)));
typedef float v4f __attribute__((ext_vector_type(4)));

__device__ __forceinline__ void exp8(const float* __restrict__ src,
                                     _Float16* __restrict__ dst) {
    float4 a = *reinterpret_cast<const float4*>(src);
    float4 b = *reinterpret_cast<const float4*>(src + 4);
    v8h o;
    o[0] = (_Float16)__expf(a.x); o[1] = (_Float16)__expf(a.y);
    o[2] = (_Float16)__expf(a.z); o[3] = (_Float16)__expf(a.w);
    o[4] = (_Float16)__expf(b.x); o[5] = (_Float16)__expf(b.y);
    o[6] = (_Float16)__expf(b.z); o[7] = (_Float16)__expf(b.w);
    *reinterpret_cast<v8h*>(dst) = o;
}

// One wave computes a 16x32 C-tile: C[m0..m0+16) x [n0..n0+32), K=512.
// A,B both row-major with K contiguous (B is [n][k], i.e. original w layout).
// A-frag: lane holds A[m0+(lane&15)][k + (lane>>4)*8 + 0..7]  (16B loads)
// C/D:    col = lane&15, row = (lane>>4)*4 + reg              (verified)
__device__ __forceinline__ void gemm_tile(const _Float16* __restrict__ A,
                                          const _Float16* __restrict__ B,
                                          int m0, int n0, int lane,
                                          v4f& c0, v4f& c1) {
    const int r = lane & 15, q = lane >> 4;
    const _Float16* a  = A + (m0 + r) * 512 + q * 8;
    const _Float16* b0 = B + (n0 + r) * 512 + q * 8;
    const _Float16* b1 = b0 + 16 * 512;
    c0 = (v4f){0.f, 0.f, 0.f, 0.f};
    c1 = c0;
#pragma unroll 4
    for (int k = 0; k < 512; k += 32) {
        v8h av  = *reinterpret_cast<const v8h*>(a + k);
        v8h bv0 = *reinterpret_cast<const v8h*>(b0 + k);
        v8h bv1 = *reinterpret_cast<const v8h*>(b1 + k);
        c0 = __builtin_amdgcn_mfma_f32_16x16x32_f16(av, bv0, c0, 0, 0, 0);
        c1 = __builtin_amdgcn_mfma_f32_16x16x32_f16(av, bv1, c1, 0, 0, 0);
    }
}

// Tropical-LN on one row (1 wave): h = log(P)+gb; exact order stats via
// in-register bitonic sort (8 elem/lane); relu; subtract rowmax; exp -> f16.
__device__ __forceinline__ void ln_row(const float* __restrict__ P,
                                       const float* __restrict__ gb,
                                       const float* __restrict__ lw,
                                       const float* __restrict__ lb,
                                       _Float16* __restrict__ E,
                                       float* __restrict__ crow,
                                       int row, int lane) {
    const float* p = P + row * 512;
    float h[8], v[8];
#pragma unroll
    for (int r = 0; r < 8; ++r) {
        int j = r * 64 + lane;
        h[r] = __logf(p[j]) + gb[j];
        v[r] = h[r];
    }
    for (int k = 2; k <= 512; k <<= 1) {
        for (int j = k >> 1; j >= 64; j >>= 1) {      // partner differs in reg
            int rj = j >> 6;
#pragma unroll
            for (int rl = 0; rl < 8; ++rl) {
                if (rl & rj) continue;
                int rh = rl | rj;
                int el = (rl << 6) | lane;
                bool up = ((el & k) == 0);
                float a = v[rl], c = v[rh];
                float lo = fminf(a, c), hi = fmaxf(a, c);
                v[rl] = up ? lo : hi;
                v[rh] = up ? hi : lo;
            }
        }
        for (int j = (k >> 1) > 32 ? 32 : (k >> 1); j > 0; j >>= 1) {  // lanes
#pragma unroll
            for (int r = 0; r < 8; ++r) {
                float pv = __shfl_xor(v[r], j);
                int e = (r << 6) | lane;
                bool up = ((e & k) == 0);
                bool low = ((lane & j) == 0);
                v[r] = (up == low) ? fminf(v[r], pv) : fmaxf(v[r], pv);
            }
        }
    }
    float s127 = __shfl(v[1], 63);
    float s128 = __shfl(v[2], 0);
    float med  = __shfl(v[3], 63);
    float s383 = __shfl(v[5], 63);
    float s384 = __shfl(v[6], 0);
    float q25 = s127 + 0.75f * (s128 - s127);
    float q75 = s383 + 0.25f * (s384 - s383);
    float inv = 1.0f / fmaxf(q75 - q25, 1e-6f);

    float y[8], cm = 0.0f;                      // y >= 0 after relu
#pragma unroll
    for (int r = 0; r < 8; ++r) {
        int j = r * 64 + lane;
        y[r] = fmaxf((h[r] - med) * inv * lw[j] + lb[j], 0.0f);
        cm = fmaxf(cm, y[r]);
    }
#pragma unroll
    for (int s = 32; s > 0; s >>= 1) cm = fmaxf(cm, __shfl_xor(cm, s));
#pragma unroll
    for (int r = 0; r < 8; ++r) {
        int j = r * 64 + lane;
        E[row * 512 + j] = (_Float16)__expf(y[r] - cm);
    }
    if (lane == 0) crow[row] = cm;
}

__global__ __launch_bounds__(256) void fused_mlp(
    const float* __restrict__ x,
    const float* __restrict__ w1, const float* __restrict__ b1,
    const float* __restrict__ ln1w, const float* __restrict__ ln1b,
    const float* __restrict__ w2, const float* __restrict__ b2,
    const float* __restrict__ ln2w, const float* __restrict__ ln2b,
    const float* __restrict__ w3, const float* __restrict__ b3,
    float* __restrict__ out,
    _Float16* __restrict__ E, _Float16* __restrict__ Ew,
    float* __restrict__ P, float* __restrict__ crow)
{
    cg::grid_group grid = cg::this_grid();
    const int tid = threadIdx.x;
    const int t = blockIdx.x * 256 + tid;            // 0..65535
    const int lane = tid & 63;
    const int gw = (blockIdx.x << 2) | (tid >> 6);   // global wave id, 0..1023

    // ---- phase E: exp of x and all weights -> f16 ----
    exp8(x + t * 8, E + t * 8);                      // 65536*8 = 524288 exactly
    for (int i = t; i < 81920; i += 65536) {         // 655360 weight elems
        int e = i * 8;
        const float* src = (e < 262144) ? w1 + e
                         : (e < 524288) ? w2 + (e - 262144)
                                        : w3 + (e - 524288);
        exp8(src, Ew + e);
    }
    grid.sync();

    // ---- layer 1 ----
    {
        int m0 = (gw & 63) * 16, n0 = (gw >> 6) * 32;
        v4f c0, c1;
        gemm_tile(E, Ew, m0, n0, lane, c0, c1);
        const int r = lane & 15, q = lane >> 4;
#pragma unroll
        for (int tt = 0; tt < 4; ++tt) {
            P[(m0 + q * 4 + tt) * 512 + n0 + r]      = c0[tt];
            P[(m0 + q * 4 + tt) * 512 + n0 + 16 + r] = c1[tt];
        }
    }
    grid.sync();
    ln_row(P, b1, ln1w, ln1b, E, crow, gw, lane);
    grid.sync();

    // ---- layer 2 ----
    {
        int m0 = (gw & 63) * 16, n0 = (gw >> 6) * 32;
        v4f c0, c1;
        gemm_tile(E, Ew + 262144, m0, n0, lane, c0, c1);
        const int r = lane & 15, q = lane >> 4;
#pragma unroll
        for (int tt = 0; tt < 4; ++tt) {
            P[(m0 + q * 4 + tt) * 512 + n0 + r]      = c0[tt];
            P[(m0 + q * 4 + tt) * 512 + n0 + 16 + r] = c1[tt];
        }
    }
    grid.sync();
    ln_row(P, b2, ln2w, ln2b, E, crow, gw, lane);
    grid.sync();

    // ---- layer 3 (N=256) + final epilogue straight to out ----
    if (gw < 512) {
        int m0 = (gw & 63) * 16, n0 = (gw >> 6) * 32;
        v4f c0, c1;
        gemm_tile(E, Ew + 524288, m0, n0, lane, c0, c1);
        const int r = lane & 15, q = lane >> 4;
        float cr[4];
#pragma unroll
        for (int tt = 0; tt < 4; ++tt) cr[tt] = crow[m0 + q * 4 + tt];
        float bb0 = b3[n0 + r], bb1 = b3[n0 + 16 + r];
#pragma unroll
        for (int tt = 0; tt < 4; ++tt) {
            int row = m0 + q * 4 + tt;
            out[row * 256 + n0 + r]      = __logf(c0[tt]) + cr[tt] + bb0;
            out[row * 256 + n0 + 16 + r] = __logf(c1[tt]) + cr[tt] + bb1;
        }
    }
}

extern "C" void kernel_launch(void* const* d_in, const int* in_sizes, int n_in,
                              void* d_out, int out_size, void* d_ws, size_t ws_size,
                              hipStream_t stream) {
    const float* x    = (const float*)d_in[0];
    const float* w1   = (const float*)d_in[1];
    const float* b1   = (const float*)d_in[2];
    const float* ln1w = (const float*)d_in[3];
    const float* ln1b = (const float*)d_in[4];
    const float* w2   = (const float*)d_in[5];
    const float* b2   = (const float*)d_in[6];
    const float* ln2w = (const float*)d_in[7];
    const float* ln2b = (const float*)d_in[8];
    const float* w3   = (const float*)d_in[9];
    const float* b3   = (const float*)d_in[10];
    float* out = (float*)d_out;

    char* ws = (char*)d_ws;
    _Float16* E    = (_Float16*)ws;                 // 1024*512 f16 = 1 MB
    _Float16* Ew   = (_Float16*)(ws + (1 << 20));   // 655360 f16  = 1.25 MB
    float*    P    = (float*)(ws + (5 << 19));      // 1024*512 f32 = 2 MB
    float*    crow = (float*)(ws + (9 << 19));      // 1024 f32

    void* args[] = {&x, &w1, &b1, &ln1w, &ln1b, &w2, &b2, &ln2w, &ln2b,
                    &w3, &b3, &out, &E, &Ew, &P, &crow};
    hipLaunchCooperativeKernel((void*)fused_mlp, dim3(256), dim3(256),
                               args, 0, stream);
}

// Round 5
// 127.509 us; speedup vs baseline: 2.3212x; 2.3212x over previous
//
#include <hip/hip_runtime.h>
#include <math.h>

// ---------------------------------------------------------------------------
// TropicalMLP: h_i = logsumexp_j(x_j + w_ij) + b_i = log(sum_j e^x_j e^w_ij)+b_i
// The network is ROW-INDEPENDENT (GEMM reduces features, LN is per-row), so one
// block owns 4 batch rows and runs all 3 layers + 2 LNs with only
// __syncthreads(). Two dispatches total: exp(weights) prep + fused kernel.
// (R4's cooperative grid.sync cost ~35us each across XCDs — removed.)
// MFMA: 4 real rows replicated 4x into the 16-row A slot (block-self-contained;
// MFMA throughput is not the bottleneck). Weights streamed f16 from L2.
// LN: exact order stats, lane-major in-register bitonic (21 shuffle rounds).
// Per-row max subtracted before exp (cancels in next LN; restored in final
// epilogue) keeps everything f16-safe.
// ---------------------------------------------------------------------------

typedef _Float16 v8h __attribute__((ext_vector_type(8)));
typedef float v4f __attribute__((ext_vector_type(4)));

// D1: exp of all three weight matrices -> f16.
// w1: 512x512 (262144), w2: 512x512 (262144), w3: 256x512 (131072).
__global__ __launch_bounds__(256) void expW_kernel(const float* __restrict__ w1,
                                                   const float* __restrict__ w2,
                                                   const float* __restrict__ w3,
                                                   _Float16* __restrict__ Ew) {
    int e = (blockIdx.x * 256 + threadIdx.x) * 8;   // 320*256*8 = 655360 exactly
    const float* src;
    if (e < 262144) src = w1 + e;
    else if (e < 524288) src = w2 + (e - 262144);
    else src = w3 + (e - 524288);
    float4 a = *reinterpret_cast<const float4*>(src);
    float4 b = *reinterpret_cast<const float4*>(src + 4);
    v8h o;
    o[0] = (_Float16)__expf(a.x); o[1] = (_Float16)__expf(a.y);
    o[2] = (_Float16)__expf(a.z); o[3] = (_Float16)__expf(a.w);
    o[4] = (_Float16)__expf(b.x); o[5] = (_Float16)__expf(b.y);
    o[6] = (_Float16)__expf(b.z); o[7] = (_Float16)__expf(b.w);
    *reinterpret_cast<v8h*>(Ew + e) = o;
}

#define ELS_STRIDE 520   // f16 elems per row in LDS A-buffer (pad breaks bank 0 pileup)

// GEMM for this block's rows: C[16(dup) x NSUB*16] over K=512.
// A from LDS (rows r&3 duplicated), B fragments streamed from global f16.
// A-frag: lane holds A[r][q*8..+8]; B-frag: B[n0+s*16+r][q*8..+8].
template <int NSUB>
__device__ __forceinline__ void gemm_rows(const _Float16* __restrict__ Bw,
                                          const _Float16* Els,
                                          int n0, int r, int q, v4f* acc) {
    const _Float16* bp = Bw + (n0 + r) * 512 + q * 8;
    const _Float16* ap = Els + (r & 3) * ELS_STRIDE + q * 8;
#pragma unroll
    for (int s = 0; s < NSUB; ++s) acc[s] = (v4f){0.f, 0.f, 0.f, 0.f};
#pragma unroll 4
    for (int k0 = 0; k0 < 512; k0 += 32) {
        v8h a = *reinterpret_cast<const v8h*>(ap + k0);
#pragma unroll
        for (int s = 0; s < NSUB; ++s) {
            v8h bv = *reinterpret_cast<const v8h*>(bp + s * 16 * 512 + k0);
            acc[s] = __builtin_amdgcn_mfma_f32_16x16x32_f16(a, bv, acc[s], 0, 0, 0);
        }
    }
}

// Lane-major bitonic sort of 512 values, element e = lane*8 + j, ascending.
// jj<8 exchanges are in-register; jj>=8 via shfl_xor (21 rounds x 8 shuffles).
__device__ __forceinline__ void sort512(float* v, int lane) {
#pragma unroll
    for (int k = 2; k <= 512; k <<= 1) {
#pragma unroll
        for (int jj = 256; jj > 0; jj >>= 1) {
            if (jj >= k) continue;
            if (jj >= 8) {
                int lm = jj >> 3;
#pragma unroll
                for (int j = 0; j < 8; ++j) {
                    float pv = __shfl_xor(v[j], lm);
                    bool up = ((((lane << 3) | j) & k) == 0);
                    bool low = ((lane & lm) == 0);
                    v[j] = (up == low) ? fminf(v[j], pv) : fmaxf(v[j], pv);
                }
            } else {
#pragma unroll
                for (int j = 0; j < 8; ++j) {
                    if (j & jj) continue;
                    int jh = j | jj;
                    bool up = ((((lane << 3) | j) & k) == 0);
                    float a = v[j], c = v[jh];
                    float lo = fminf(a, c), hi = fmaxf(a, c);
                    v[j] = up ? lo : hi;
                    v[jh] = up ? hi : lo;
                }
            }
        }
    }
}

__global__ __launch_bounds__(256) void fused_rows(
    const float* __restrict__ x,
    const float* __restrict__ b1,
    const float* __restrict__ ln1w, const float* __restrict__ ln1b,
    const float* __restrict__ b2,
    const float* __restrict__ ln2w, const float* __restrict__ ln2b,
    const float* __restrict__ b3,
    const _Float16* __restrict__ Ew,
    float* __restrict__ out)
{
    __shared__ _Float16 Els[4 * ELS_STRIDE];   // exp'd activations (f16)
    __shared__ float hbuf[4 * 512];            // pre-LN layer output
    __shared__ float crow[4];                  // per-row shift (last LN)

    const int tid = threadIdx.x;
    const int lane = tid & 63;
    const int w = tid >> 6;                    // wave id = row id 0..3
    const int r = lane & 15, q = lane >> 4;
    const int blk = blockIdx.x;                // rows 4*blk .. 4*blk+4

    const _Float16* Ew1 = Ew;
    const _Float16* Ew2 = Ew + 262144;
    const _Float16* Ew3 = Ew + 524288;

    // ---- phase 0: exp(x) for this block's 4 rows -> Els ----
    {
        const float* src = x + blk * 2048 + tid * 8;   // row=tid>>6, col=lane*8
        float4 a = *reinterpret_cast<const float4*>(src);
        float4 b = *reinterpret_cast<const float4*>(src + 4);
        v8h o;
        o[0] = (_Float16)__expf(a.x); o[1] = (_Float16)__expf(a.y);
        o[2] = (_Float16)__expf(a.z); o[3] = (_Float16)__expf(a.w);
        o[4] = (_Float16)__expf(b.x); o[5] = (_Float16)__expf(b.y);
        o[6] = (_Float16)__expf(b.z); o[7] = (_Float16)__expf(b.w);
        *reinterpret_cast<v8h*>(&Els[w * ELS_STRIDE + lane * 8]) = o;
    }
    __syncthreads();

    v4f acc[8];
    // ===== layer 1: GEMM (wave covers cols w*128..+128) + log+bias -> hbuf =====
    gemm_rows<8>(Ew1, Els, w * 128, r, q, acc);
    if (q == 0) {
#pragma unroll
        for (int s = 0; s < 8; ++s) {
            int col = w * 128 + s * 16 + r;
            float bb = b1[col];
#pragma unroll
            for (int t = 0; t < 4; ++t)
                hbuf[t * 512 + col] = __logf(acc[s][t]) + bb;
        }
    }
    __syncthreads();

    // ===== LN1 (wave w handles row w) =====
#pragma unroll 1
    for (int layer = 0; layer < 2; ++layer) {
        const float* lw = layer ? ln2w : ln1w;
        const float* lb = layer ? ln2b : ln1b;
        float h[8], v[8];
        {
            const float* hp = hbuf + w * 512 + lane * 8;
            float4 a = *reinterpret_cast<const float4*>(hp);
            float4 b = *reinterpret_cast<const float4*>(hp + 4);
            h[0] = a.x; h[1] = a.y; h[2] = a.z; h[3] = a.w;
            h[4] = b.x; h[5] = b.y; h[6] = b.z; h[7] = b.w;
#pragma unroll
            for (int j = 0; j < 8; ++j) v[j] = h[j];
        }
        sort512(v, lane);
        float s127 = __shfl(v[7], 15);
        float s128 = __shfl(v[0], 16);
        float med  = __shfl(v[7], 31);
        float s383 = __shfl(v[7], 47);
        float s384 = __shfl(v[0], 48);
        float q25 = s127 + 0.75f * (s128 - s127);
        float q75 = s383 + 0.25f * (s384 - s383);
        float inv = 1.0f / fmaxf(q75 - q25, 1e-6f);

        float y[8], cm = 0.0f;                  // y >= 0 after relu
        {
            const float4* lw4 = reinterpret_cast<const float4*>(lw + lane * 8);
            const float4* lb4 = reinterpret_cast<const float4*>(lb + lane * 8);
            float4 wa = lw4[0], wb = lw4[1], ba = lb4[0], bb = lb4[1];
            float lwv[8] = {wa.x, wa.y, wa.z, wa.w, wb.x, wb.y, wb.z, wb.w};
            float lbv[8] = {ba.x, ba.y, ba.z, ba.w, bb.x, bb.y, bb.z, bb.w};
#pragma unroll
            for (int j = 0; j < 8; ++j) {
                y[j] = fmaxf((h[j] - med) * inv * lwv[j] + lbv[j], 0.0f);
                cm = fmaxf(cm, y[j]);
            }
        }
#pragma unroll
        for (int s = 32; s > 0; s >>= 1) cm = fmaxf(cm, __shfl_xor(cm, s));
        {
            v8h o;
#pragma unroll
            for (int j = 0; j < 8; ++j) o[j] = (_Float16)__expf(y[j] - cm);
            *reinterpret_cast<v8h*>(&Els[w * ELS_STRIDE + lane * 8]) = o;
        }
        if (lane == 0) crow[w] = cm;
        __syncthreads();

        // ===== next GEMM: layer 2 (->hbuf) or layer 3 (->out) =====
        if (layer == 0) {
            gemm_rows<8>(Ew2, Els, w * 128, r, q, acc);
            if (q == 0) {
#pragma unroll
                for (int s = 0; s < 8; ++s) {
                    int col = w * 128 + s * 16 + r;
                    float bb = b2[col];
#pragma unroll
                    for (int t = 0; t < 4; ++t)
                        hbuf[t * 512 + col] = __logf(acc[s][t]) + bb;
                }
            }
            __syncthreads();
        } else {
            gemm_rows<4>(Ew3, Els, w * 64, r, q, acc);   // N = 256
            if (q == 0) {
#pragma unroll
                for (int s = 0; s < 4; ++s) {
                    int col = w * 64 + s * 16 + r;
                    float bb = b3[col];
#pragma unroll
                    for (int t = 0; t < 4; ++t)
                        out[(blk * 4 + t) * 256 + col] =
                            __logf(acc[s][t]) + crow[t] + bb;
                }
            }
        }
    }
}

extern "C" void kernel_launch(void* const* d_in, const int* in_sizes, int n_in,
                              void* d_out, int out_size, void* d_ws, size_t ws_size,
                              hipStream_t stream) {
    const float* x    = (const float*)d_in[0];
    const float* w1   = (const float*)d_in[1];
    const float* b1   = (const float*)d_in[2];
    const float* ln1w = (const float*)d_in[3];
    const float* ln1b = (const float*)d_in[4];
    const float* w2   = (const float*)d_in[5];
    const float* b2   = (const float*)d_in[6];
    const float* ln2w = (const float*)d_in[7];
    const float* ln2b = (const float*)d_in[8];
    const float* w3   = (const float*)d_in[9];
    const float* b3   = (const float*)d_in[10];
    float* out = (float*)d_out;

    _Float16* Ew = (_Float16*)d_ws;            // 655360 f16 = 1.25 MB

    expW_kernel<<<320, 256, 0, stream>>>(w1, w2, w3, Ew);
    fused_rows<<<256, 256, 0, stream>>>(x, b1, ln1w, ln1b, b2, ln2w, ln2b,
                                        b3, Ew, out);
}

// Round 6
// 100.977 us; speedup vs baseline: 2.9311x; 1.2627x over previous
//
#include <hip/hip_runtime.h>
#include <math.h>

// ---------------------------------------------------------------------------
// TropicalMLP: h_i = logsumexp_j(x_j + w_ij) + b_i = log(sum_j e^x_j e^w_ij)+b_i
// Row-independent network: one block owns 4 batch rows and runs all 3 layers +
// 2 tropical-LNs with only __syncthreads(). Two dispatches:
//   D1 expW_frag: exp(w)->f16, permuted into MFMA-fragment order so every
//      B-load in the GEMM is one coalesced 1KB wave load (R5's B-loads touched
//      16 scattered 64B lines each -> ~30us of exposed L2 latency).
//   D2 fused_rows: 512 thr/block (8 waves -> 2/SIMD, R5 had 1/SIMD), depth-4
//      register pipeline on B, A-operand preloaded to registers per layer.
// LN: exact order stats, lane-major in-register bitonic (21 shuffle rounds).
// Per-row max subtracted before exp (cancels in next LN; restored in final
// epilogue) keeps everything f16-safe.
// ---------------------------------------------------------------------------

typedef _Float16 v8h __attribute__((ext_vector_type(8)));
typedef _Float16 v4h __attribute__((ext_vector_type(4)));
typedef float v4f __attribute__((ext_vector_type(4)));

#define ELS_STRIDE 528   // f16/row in LDS A-buffer; 1056B = 16B-aligned, 2-way-free banks

// D1: exp + f16 + fragment reorder. Global tile S (16 cols), k-step t (32 k),
// lane l = q*16+r:  Ef[((S*16+t)*64+l)*8 + j] = exp(W[S*16+r][t*32+q*8+j]).
// S: 0..31 -> w1, 32..63 -> w2, 64..79 -> w3 (output stays contiguous per layer).
__global__ __launch_bounds__(256) void expW_frag(const float* __restrict__ w1,
                                                 const float* __restrict__ w2,
                                                 const float* __restrict__ w3,
                                                 _Float16* __restrict__ Ef) {
    int u = blockIdx.x * 256 + threadIdx.x;          // 0..81919 (320 blocks)
    int lane = u & 63, t = (u >> 6) & 15, S = u >> 10;
    int r = lane & 15, q = lane >> 4;
    const float* w; int tile;
    if (S < 32)      { w = w1; tile = S; }
    else if (S < 64) { w = w2; tile = S - 32; }
    else             { w = w3; tile = S - 64; }
    const float* src = w + (tile * 16 + r) * 512 + t * 32 + q * 8;
    float4 a = *reinterpret_cast<const float4*>(src);
    float4 b = *reinterpret_cast<const float4*>(src + 4);
    v8h o;
    o[0] = (_Float16)__expf(a.x); o[1] = (_Float16)__expf(a.y);
    o[2] = (_Float16)__expf(a.z); o[3] = (_Float16)__expf(a.w);
    o[4] = (_Float16)__expf(b.x); o[5] = (_Float16)__expf(b.y);
    o[6] = (_Float16)__expf(b.z); o[7] = (_Float16)__expf(b.w);
    *reinterpret_cast<v8h*>(Ef + u * 8) = o;
}

// Preload the whole A operand (this block's 4 rows, dup 4x in the 16-row slot)
// for all 16 k-steps into registers: 16 x ds_read_b128.
__device__ __forceinline__ void load_areg(const _Float16* Els, int lane, v8h* areg) {
    const int r = lane & 15, q = lane >> 4;
    const _Float16* ap = Els + (r & 3) * ELS_STRIDE + q * 8;
#pragma unroll
    for (int t = 0; t < 16; ++t)
        areg[t] = *reinterpret_cast<const v8h*>(ap + t * 32);
}

// C[16(dup rows) x NSUB*16 cols] over K=512. B from fragment-ordered global
// (1KB coalesced per load), depth-4 rotating register pipeline.
template <int NSUB>
__device__ __forceinline__ void gemm_frag(const _Float16* __restrict__ Bf,
                                          int s0, int lane,
                                          const v8h* areg, v4f* acc) {
    const _Float16* bp = Bf + lane * 8;
    v8h bb[4][NSUB];
#pragma unroll
    for (int p = 0; p < 3; ++p)
#pragma unroll
        for (int s = 0; s < NSUB; ++s)
            bb[p][s] = *reinterpret_cast<const v8h*>(bp + ((s0 + s) * 16 + p) * 512);
#pragma unroll
    for (int s = 0; s < NSUB; ++s) acc[s] = (v4f){0.f, 0.f, 0.f, 0.f};
#pragma unroll
    for (int t = 0; t < 16; ++t) {
        if (t + 3 < 16) {
#pragma unroll
            for (int s = 0; s < NSUB; ++s)
                bb[(t + 3) & 3][s] =
                    *reinterpret_cast<const v8h*>(bp + ((s0 + s) * 16 + t + 3) * 512);
        }
#pragma unroll
        for (int s = 0; s < NSUB; ++s)
            acc[s] = __builtin_amdgcn_mfma_f32_16x16x32_f16(areg[t], bb[t & 3][s],
                                                            acc[s], 0, 0, 0);
    }
}

// Tropical-LN on one row (1 wave, lane-major): h from hbuf; exact order stats
// via in-register bitonic; relu; subtract rowmax; exp -> f16 into Els.
__device__ __forceinline__ void ln_row(const float* hbuf,
                                       const float* __restrict__ lw,
                                       const float* __restrict__ lb,
                                       _Float16* Els, float* crow,
                                       int w, int lane) {
    float h[8], v[8];
    {
        const float* hp = hbuf + w * 512 + lane * 8;
        float4 a = *reinterpret_cast<const float4*>(hp);
        float4 b = *reinterpret_cast<const float4*>(hp + 4);
        h[0] = a.x; h[1] = a.y; h[2] = a.z; h[3] = a.w;
        h[4] = b.x; h[5] = b.y; h[6] = b.z; h[7] = b.w;
#pragma unroll
        for (int j = 0; j < 8; ++j) v[j] = h[j];
    }
    // Bitonic sort, element e = lane*8 + j, ascending.
#pragma unroll
    for (int k = 2; k <= 512; k <<= 1) {
#pragma unroll
        for (int jj = 256; jj > 0; jj >>= 1) {
            if (jj >= k) continue;
            if (jj >= 8) {
                int lm = jj >> 3;
#pragma unroll
                for (int j = 0; j < 8; ++j) {
                    float pv = __shfl_xor(v[j], lm);
                    bool up = ((((lane << 3) | j) & k) == 0);
                    bool low = ((lane & lm) == 0);
                    v[j] = (up == low) ? fminf(v[j], pv) : fmaxf(v[j], pv);
                }
            } else {
#pragma unroll
                for (int j = 0; j < 8; ++j) {
                    if (j & jj) continue;
                    int jh = j | jj;
                    bool up = ((((lane << 3) | j) & k) == 0);
                    float a = v[j], c = v[jh];
                    float lo = fminf(a, c), hi = fmaxf(a, c);
                    v[j] = up ? lo : hi;
                    v[jh] = up ? hi : lo;
                }
            }
        }
    }
    float s127 = __shfl(v[7], 15);
    float s128 = __shfl(v[0], 16);
    float med  = __shfl(v[7], 31);
    float s383 = __shfl(v[7], 47);
    float s384 = __shfl(v[0], 48);
    float q25 = s127 + 0.75f * (s128 - s127);
    float q75 = s383 + 0.25f * (s384 - s383);
    float inv = 1.0f / fmaxf(q75 - q25, 1e-6f);

    float y[8], cm = 0.0f;                      // y >= 0 after relu
    {
        const float4* lw4 = reinterpret_cast<const float4*>(lw + lane * 8);
        const float4* lb4 = reinterpret_cast<const float4*>(lb + lane * 8);
        float4 wa = lw4[0], wb = lw4[1], ba = lb4[0], bbv = lb4[1];
        float lwv[8] = {wa.x, wa.y, wa.z, wa.w, wb.x, wb.y, wb.z, wb.w};
        float lbv[8] = {ba.x, ba.y, ba.z, ba.w, bbv.x, bbv.y, bbv.z, bbv.w};
#pragma unroll
        for (int j = 0; j < 8; ++j) {
            y[j] = fmaxf((h[j] - med) * inv * lwv[j] + lbv[j], 0.0f);
            cm = fmaxf(cm, y[j]);
        }
    }
#pragma unroll
    for (int s = 32; s > 0; s >>= 1) cm = fmaxf(cm, __shfl_xor(cm, s));
    {
        v8h o;
#pragma unroll
        for (int j = 0; j < 8; ++j) o[j] = (_Float16)__expf(y[j] - cm);
        *reinterpret_cast<v8h*>(&Els[w * ELS_STRIDE + lane * 8]) = o;
    }
    if (lane == 0) crow[w] = cm;
}

__global__ __launch_bounds__(512, 2) void fused_rows(
    const float* __restrict__ x,
    const float* __restrict__ b1,
    const float* __restrict__ ln1w, const float* __restrict__ ln1b,
    const float* __restrict__ b2,
    const float* __restrict__ ln2w, const float* __restrict__ ln2b,
    const float* __restrict__ b3,
    const _Float16* __restrict__ Ew,
    float* __restrict__ out)
{
    __shared__ _Float16 Els[4 * ELS_STRIDE];   // exp'd activations (f16)
    __shared__ float hbuf[4 * 512];            // pre-LN layer output
    __shared__ float crow[4];                  // per-row shift (last LN)

    const int tid = threadIdx.x;
    const int lane = tid & 63;
    const int w = tid >> 6;                    // wave id 0..7
    const int r = lane & 15, q = lane >> 4;
    const int blk = blockIdx.x;                // rows 4*blk .. 4*blk+3

    // ---- phase 0: exp(x) for this block's 4 rows -> Els (4 elems/thread) ----
    {
        int row = tid >> 7, col = (tid & 127) * 4;
        float4 a = *reinterpret_cast<const float4*>(x + blk * 2048 + row * 512 + col);
        v4h o;
        o[0] = (_Float16)__expf(a.x); o[1] = (_Float16)__expf(a.y);
        o[2] = (_Float16)__expf(a.z); o[3] = (_Float16)__expf(a.w);
        *reinterpret_cast<v4h*>(&Els[row * ELS_STRIDE + col]) = o;
    }
    __syncthreads();

    v8h areg[16];
    v4f acc[4];

    // ===== layer 1: wave w covers cols w*64..w*64+64 (tiles w*4..w*4+4) =====
    load_areg(Els, lane, areg);
    gemm_frag<4>(Ew, w * 4, lane, areg, acc);
    if (q == 0) {
#pragma unroll
        for (int s = 0; s < 4; ++s) {
            int col = (w * 4 + s) * 16 + r;
            float bb = b1[col];
#pragma unroll
            for (int t = 0; t < 4; ++t)
                hbuf[t * 512 + col] = __logf(acc[s][t]) + bb;
        }
    }
    __syncthreads();
    if (w < 4) ln_row(hbuf, ln1w, ln1b, Els, crow, w, lane);
    __syncthreads();

    // ===== layer 2 =====
    load_areg(Els, lane, areg);
    gemm_frag<4>(Ew + 262144, w * 4, lane, areg, acc);
    if (q == 0) {
#pragma unroll
        for (int s = 0; s < 4; ++s) {
            int col = (w * 4 + s) * 16 + r;
            float bb = b2[col];
#pragma unroll
            for (int t = 0; t < 4; ++t)
                hbuf[t * 512 + col] = __logf(acc[s][t]) + bb;
        }
    }
    __syncthreads();
    if (w < 4) ln_row(hbuf, ln2w, ln2b, Els, crow, w, lane);
    __syncthreads();

    // ===== layer 3 (N=256, tiles w*2..w*2+2) + epilogue straight to out =====
    load_areg(Els, lane, areg);
    gemm_frag<2>(Ew + 524288, w * 2, lane, areg, acc);
    if (q == 0) {
#pragma unroll
        for (int s = 0; s < 2; ++s) {
            int col = (w * 2 + s) * 16 + r;
            float bb = b3[col];
#pragma unroll
            for (int t = 0; t < 4; ++t)
                out[(blk * 4 + t) * 256 + col] = __logf(acc[s][t]) + crow[t] + bb;
        }
    }
}

extern "C" void kernel_launch(void* const* d_in, const int* in_sizes, int n_in,
                              void* d_out, int out_size, void* d_ws, size_t ws_size,
                              hipStream_t stream) {
    const float* x    = (const float*)d_in[0];
    const float* w1   = (const float*)d_in[1];
    const float* b1   = (const float*)d_in[2];
    const float* ln1w = (const float*)d_in[3];
    const float* ln1b = (const float*)d_in[4];
    const float* w2   = (const float*)d_in[5];
    const float* b2   = (const float*)d_in[6];
    const float* ln2w = (const float*)d_in[7];
    const float* ln2b = (const float*)d_in[8];
    const float* w3   = (const float*)d_in[9];
    const float* b3   = (const float*)d_in[10];
    float* out = (float*)d_out;

    _Float16* Ew = (_Float16*)d_ws;            // 655360 f16 = 1.25 MB

    expW_frag<<<320, 256, 0, stream>>>(w1, w2, w3, Ew);
    fused_rows<<<256, 512, 0, stream>>>(x, b1, ln1w, ln1b, b2, ln2w, ln2b,
                                        b3, Ew, out);
}

// Round 7
// 97.986 us; speedup vs baseline: 3.0206x; 1.0305x over previous
//
#include <hip/hip_runtime.h>
#include <math.h>

// ---------------------------------------------------------------------------
// TropicalMLP: h_i = logsumexp_j(x_j + w_ij) + b_i = log(sum_j e^x_j e^w_ij)+b_i
// Row-independent network: one block owns 4 batch rows, runs all 3 layers +
// 2 tropical-LNs with only __syncthreads(). Two dispatches.
// R7: fp8 e4m3 operands (halves the per-block 1.25MB weight stream -> GEMM
// floor ~4.3us) via mfma_f32_16x16x32_fp8_fp8. Scaling keeps everything in
// fp8's normal range: layer1 A = 4*exp(x) (+ln4 cancels in LN1 median);
// layers2/3 A = 64*exp(y-cm) (+ln64 cancels in LN2; subtracted in final
// epilogue). B = exp(w) in [0.6,1.6] needs no scale.
// Weights pre-exp'd + permuted to MFMA-fragment order (1KB-coalesced loads),
// depth-8 register pipeline on B; whole A operand preloaded per layer.
// LN: exact order stats, lane-major in-register bitonic (21 shuffle rounds).
// ---------------------------------------------------------------------------

typedef float v4f __attribute__((ext_vector_type(4)));

#define ELS_B 528                  // bytes per LDS A-row (16B pad: 2-way banks = free)
#define LN64f 4.1588830833596715f  // ln(64)

__device__ __forceinline__ int pk4_fp8(float a, float b, float c, float d) {
    int p = __builtin_amdgcn_cvt_pk_fp8_f32(a, b, 0, 0);      // bytes 0,1
    p = __builtin_amdgcn_cvt_pk_fp8_f32(c, d, p, 1);          // bytes 2,3
    return p;
}

// D1: exp + fp8 + fragment reorder. Global 16-col tile S, k-step t (32 k),
// lane l = q*16+r:  Ef[(S*16+t)*512 + l*8 + j] = fp8(exp(W[S*16+r][t*32+q*8+j]))
// S: 0..31 -> w1, 32..63 -> w2, 64..79 -> w3 (contiguous per layer, in bytes).
__global__ __launch_bounds__(256) void expW_frag(const float* __restrict__ w1,
                                                 const float* __restrict__ w2,
                                                 const float* __restrict__ w3,
                                                 uint8_t* __restrict__ Ef) {
    int u = blockIdx.x * 256 + threadIdx.x;          // 0..81919 (320 blocks)
    int lane = u & 63, t = (u >> 6) & 15, S = u >> 10;
    int r = lane & 15, q = lane >> 4;
    const float* w; int tile;
    if (S < 32)      { w = w1; tile = S; }
    else if (S < 64) { w = w2; tile = S - 32; }
    else             { w = w3; tile = S - 64; }
    const float* src = w + (tile * 16 + r) * 512 + t * 32 + q * 8;
    float4 a = *reinterpret_cast<const float4*>(src);
    float4 b = *reinterpret_cast<const float4*>(src + 4);
    int2 o;
    o.x = pk4_fp8(__expf(a.x), __expf(a.y), __expf(a.z), __expf(a.w));
    o.y = pk4_fp8(__expf(b.x), __expf(b.y), __expf(b.z), __expf(b.w));
    *reinterpret_cast<int2*>(Ef + u * 8) = o;
}

// Preload whole A operand (4 rows dup'd 4x in the 16-row slot) for all 16
// k-steps: 16 x ds_read_b64.
__device__ __forceinline__ void load_areg(const uint8_t* Els, int lane, long* areg) {
    const uint8_t* ap = Els + (lane & 3) * ELS_B + ((lane >> 4) & 3) * 8;
#pragma unroll
    for (int t = 0; t < 16; ++t)
        areg[t] = *reinterpret_cast<const long*>(ap + t * 32);
}

// C[16(dup rows) x NSUB*16 cols] over K=512, fp8 MFMA. B from fragment-ordered
// global (512B coalesced per wave-load), depth-8 register pipeline.
template <int NSUB>
__device__ __forceinline__ void gemm_frag(const uint8_t* __restrict__ Bf,
                                          int s0, int lane,
                                          const long* areg, v4f* acc) {
    const uint8_t* bp = Bf + lane * 8;
    long bb[8][NSUB];
#pragma unroll
    for (int p = 0; p < 8; ++p)
#pragma unroll
        for (int s = 0; s < NSUB; ++s)
            bb[p][s] = *reinterpret_cast<const long*>(bp + ((s0 + s) * 16 + p) * 512);
#pragma unroll
    for (int s = 0; s < NSUB; ++s) acc[s] = (v4f){0.f, 0.f, 0.f, 0.f};
#pragma unroll
    for (int t = 0; t < 16; ++t) {
        long a = areg[t];
        long bcur[NSUB];
#pragma unroll
        for (int s = 0; s < NSUB; ++s) bcur[s] = bb[t & 7][s];
        if (t < 8) {
#pragma unroll
            for (int s = 0; s < NSUB; ++s)
                bb[t & 7][s] =
                    *reinterpret_cast<const long*>(bp + ((s0 + s) * 16 + t + 8) * 512);
        }
#pragma unroll
        for (int s = 0; s < NSUB; ++s)
            acc[s] = __builtin_amdgcn_mfma_f32_16x16x32_fp8_fp8(a, bcur[s],
                                                                acc[s], 0, 0, 0);
    }
}

// Tropical-LN on one row (1 wave, lane-major): exact order stats via
// in-register bitonic; relu; subtract rowmax; 64*exp -> fp8 into Els.
__device__ __forceinline__ void ln_row(const float* hbuf,
                                       const float* __restrict__ lw,
                                       const float* __restrict__ lb,
                                       uint8_t* Els, float* crow,
                                       int w, int lane) {
    float h[8], v[8];
    {
        const float* hp = hbuf + w * 512 + lane * 8;
        float4 a = *reinterpret_cast<const float4*>(hp);
        float4 b = *reinterpret_cast<const float4*>(hp + 4);
        h[0] = a.x; h[1] = a.y; h[2] = a.z; h[3] = a.w;
        h[4] = b.x; h[5] = b.y; h[6] = b.z; h[7] = b.w;
#pragma unroll
        for (int j = 0; j < 8; ++j) v[j] = h[j];
    }
    // Bitonic sort of 512 values, element e = lane*8 + j, ascending.
#pragma unroll
    for (int k = 2; k <= 512; k <<= 1) {
#pragma unroll
        for (int jj = 256; jj > 0; jj >>= 1) {
            if (jj >= k) continue;
            if (jj >= 8) {
                int lm = jj >> 3;
#pragma unroll
                for (int j = 0; j < 8; ++j) {
                    float pv = __shfl_xor(v[j], lm);
                    bool up = ((((lane << 3) | j) & k) == 0);
                    bool low = ((lane & lm) == 0);
                    v[j] = (up == low) ? fminf(v[j], pv) : fmaxf(v[j], pv);
                }
            } else {
#pragma unroll
                for (int j = 0; j < 8; ++j) {
                    if (j & jj) continue;
                    int jh = j | jj;
                    bool up = ((((lane << 3) | j) & k) == 0);
                    float a = v[j], c = v[jh];
                    float lo = fminf(a, c), hi = fmaxf(a, c);
                    v[j] = up ? lo : hi;
                    v[jh] = up ? hi : lo;
                }
            }
        }
    }
    float s127 = __shfl(v[7], 15);
    float s128 = __shfl(v[0], 16);
    float med  = __shfl(v[7], 31);
    float s383 = __shfl(v[7], 47);
    float s384 = __shfl(v[0], 48);
    float q25 = s127 + 0.75f * (s128 - s127);
    float q75 = s383 + 0.25f * (s384 - s383);
    float inv = 1.0f / fmaxf(q75 - q25, 1e-6f);

    float y[8], cm = 0.0f;                      // y >= 0 after relu
    {
        const float4* lw4 = reinterpret_cast<const float4*>(lw + lane * 8);
        const float4* lb4 = reinterpret_cast<const float4*>(lb + lane * 8);
        float4 wa = lw4[0], wb = lw4[1], ba = lb4[0], bbv = lb4[1];
        float lwv[8] = {wa.x, wa.y, wa.z, wa.w, wb.x, wb.y, wb.z, wb.w};
        float lbv[8] = {ba.x, ba.y, ba.z, ba.w, bbv.x, bbv.y, bbv.z, bbv.w};
#pragma unroll
        for (int j = 0; j < 8; ++j) {
            y[j] = fmaxf((h[j] - med) * inv * lwv[j] + lbv[j], 0.0f);
            cm = fmaxf(cm, y[j]);
        }
    }
#pragma unroll
    for (int s = 32; s > 0; s >>= 1) cm = fmaxf(cm, __shfl_xor(cm, s));
    {
        float e[8];
#pragma unroll
        for (int j = 0; j < 8; ++j) e[j] = 64.0f * __expf(y[j] - cm);
        int2 o;
        o.x = pk4_fp8(e[0], e[1], e[2], e[3]);
        o.y = pk4_fp8(e[4], e[5], e[6], e[7]);
        *reinterpret_cast<int2*>(&Els[w * ELS_B + lane * 8]) = o;
    }
    if (lane == 0) crow[w] = cm;
}

__global__ __launch_bounds__(512, 2) void fused_rows(
    const float* __restrict__ x,
    const float* __restrict__ b1,
    const float* __restrict__ ln1w, const float* __restrict__ ln1b,
    const float* __restrict__ b2,
    const float* __restrict__ ln2w, const float* __restrict__ ln2b,
    const float* __restrict__ b3,
    const uint8_t* __restrict__ Ew,
    float* __restrict__ out)
{
    __shared__ uint8_t Els[4 * ELS_B];         // fp8 activations
    __shared__ float hbuf[4 * 512];            // pre-LN layer output
    __shared__ float crow[4];                  // per-row shift (last LN)

    const int tid = threadIdx.x;
    const int lane = tid & 63;
    const int w = tid >> 6;                    // wave id 0..7
    const int r = lane & 15, q = lane >> 4;
    const int blk = blockIdx.x;                // rows 4*blk .. 4*blk+3

    // ---- phase 0: A1 = fp8(4*exp(x)) for this block's 4 rows ----
    // (+ln4 shift cancels in LN1's median subtraction; keeps fp8 normal-range)
    {
        int row = tid >> 7, col = (tid & 127) * 4;
        float4 a = *reinterpret_cast<const float4*>(x + blk * 2048 + row * 512 + col);
        *reinterpret_cast<int*>(&Els[row * ELS_B + col]) =
            pk4_fp8(4.0f * __expf(a.x), 4.0f * __expf(a.y),
                    4.0f * __expf(a.z), 4.0f * __expf(a.w));
    }
    __syncthreads();

    long areg[16];
    v4f acc[4];

    // ===== layer 1: wave w covers cols w*64..w*64+64 (tiles w*4..w*4+4) =====
    load_areg(Els, lane, areg);
    gemm_frag<4>(Ew, w * 4, lane, areg, acc);
    if (q == 0) {
#pragma unroll
        for (int s = 0; s < 4; ++s) {
            int col = (w * 4 + s) * 16 + r;
            float bb = b1[col];
#pragma unroll
            for (int t = 0; t < 4; ++t)
                hbuf[t * 512 + col] = __logf(acc[s][t]) + bb;
        }
    }
    __syncthreads();
    if (w < 4) ln_row(hbuf, ln1w, ln1b, Els, crow, w, lane);
    __syncthreads();

    // ===== layer 2 (uniform ln64 - cm1 shift absorbed by LN2's median) =====
    load_areg(Els, lane, areg);
    gemm_frag<4>(Ew + 262144, w * 4, lane, areg, acc);
    if (q == 0) {
#pragma unroll
        for (int s = 0; s < 4; ++s) {
            int col = (w * 4 + s) * 16 + r;
            float bb = b2[col];
#pragma unroll
            for (int t = 0; t < 4; ++t)
                hbuf[t * 512 + col] = __logf(acc[s][t]) + bb;
        }
    }
    __syncthreads();
    if (w < 4) ln_row(hbuf, ln2w, ln2b, Els, crow, w, lane);
    __syncthreads();

    // ===== layer 3 (N=256, tiles w*2..w*2+2): out = log(acc)+cm2-ln64+b3 =====
    load_areg(Els, lane, areg);
    gemm_frag<2>(Ew + 524288, w * 2, lane, areg, acc);
    if (q == 0) {
#pragma unroll
        for (int s = 0; s < 2; ++s) {
            int col = (w * 2 + s) * 16 + r;
            float bb = b3[col] - LN64f;
#pragma unroll
            for (int t = 0; t < 4; ++t)
                out[(blk * 4 + t) * 256 + col] = __logf(acc[s][t]) + crow[t] + bb;
        }
    }
}

extern "C" void kernel_launch(void* const* d_in, const int* in_sizes, int n_in,
                              void* d_out, int out_size, void* d_ws, size_t ws_size,
                              hipStream_t stream) {
    const float* x    = (const float*)d_in[0];
    const float* w1   = (const float*)d_in[1];
    const float* b1   = (const float*)d_in[2];
    const float* ln1w = (const float*)d_in[3];
    const float* ln1b = (const float*)d_in[4];
    const float* w2   = (const float*)d_in[5];
    const float* b2   = (const float*)d_in[6];
    const float* ln2w = (const float*)d_in[7];
    const float* ln2b = (const float*)d_in[8];
    const float* w3   = (const float*)d_in[9];
    const float* b3   = (const float*)d_in[10];
    float* out = (float*)d_out;

    uint8_t* Ew = (uint8_t*)d_ws;              // 655360 B fp8 = 640 KB

    expW_frag<<<320, 256, 0, stream>>>(w1, w2, w3, Ew);
    fused_rows<<<256, 512, 0, stream>>>(x, b1, ln1w, ln1b, b2, ln2w, ln2b,
                                        b3, Ew, out);
}

// Round 8
// 94.885 us; speedup vs baseline: 3.1193x; 1.0327x over previous
//
#include <hip/hip_runtime.h>
#include <math.h>

// ---------------------------------------------------------------------------
// TropicalMLP: h_i = logsumexp_j(x_j + w_ij) + b_i = log(sum_j e^x_j e^w_ij)+b_i
// Row-independent network: one block owns 4 batch rows, runs all 3 layers +
// 2 tropical-LNs with only __syncthreads(). Two dispatches.
// fp8 e4m3 operands (640KB/block weight stream) via mfma_f32_16x16x32_fp8_fp8.
// Scaling keeps fp8 normal-range: layer1 A = 4*exp(x) (+ln4 cancels in LN1
// median); layers2/3 A = 64*exp(y-cm) (+ln64 cancels in LN2; subtracted in
// final epilogue). B = exp(w) in [0.6,1.6] needs no scale.
// Weights pre-exp'd + permuted to MFMA-fragment order (512B-coalesced loads).
// R8: B-prefetch for each layer hoisted ABOVE the preceding barrier --
// layer-1's overlaps the exp(x) prologue, layer-2/3's overlap the epilogue +
// barrier drain + LN, removing ~600cyc lead-in latency per GEMM from the
// serial chain. LN lw/lb loads hoisted ahead of the sort. Math identical.
// LN: exact order stats, lane-major in-register bitonic (21 shuffle rounds).
// ---------------------------------------------------------------------------

typedef float v4f __attribute__((ext_vector_type(4)));

#define ELS_B 528                  // bytes per LDS A-row (16B pad: 2-way banks = free)
#define LN64f 4.1588830833596715f  // ln(64)

__device__ __forceinline__ int pk4_fp8(float a, float b, float c, float d) {
    int p = __builtin_amdgcn_cvt_pk_fp8_f32(a, b, 0, 0);      // bytes 0,1
    p = __builtin_amdgcn_cvt_pk_fp8_f32(c, d, p, 1);          // bytes 2,3
    return p;
}

// D1: exp + fp8 + fragment reorder. Global 16-col tile S, k-step t (32 k),
// lane l = q*16+r:  Ef[(S*16+t)*512 + l*8 + j] = fp8(exp(W[S*16+r][t*32+q*8+j]))
// S: 0..31 -> w1, 32..63 -> w2, 64..79 -> w3 (contiguous per layer, in bytes).
__global__ __launch_bounds__(256) void expW_frag(const float* __restrict__ w1,
                                                 const float* __restrict__ w2,
                                                 const float* __restrict__ w3,
                                                 uint8_t* __restrict__ Ef) {
    int u = blockIdx.x * 256 + threadIdx.x;          // 0..81919 (320 blocks)
    int lane = u & 63, t = (u >> 6) & 15, S = u >> 10;
    int r = lane & 15, q = lane >> 4;
    const float* w; int tile;
    if (S < 32)      { w = w1; tile = S; }
    else if (S < 64) { w = w2; tile = S - 32; }
    else             { w = w3; tile = S - 64; }
    const float* src = w + (tile * 16 + r) * 512 + t * 32 + q * 8;
    float4 a = *reinterpret_cast<const float4*>(src);
    float4 b = *reinterpret_cast<const float4*>(src + 4);
    int2 o;
    o.x = pk4_fp8(__expf(a.x), __expf(a.y), __expf(a.z), __expf(a.w));
    o.y = pk4_fp8(__expf(b.x), __expf(b.y), __expf(b.z), __expf(b.w));
    *reinterpret_cast<int2*>(Ef + u * 8) = o;
}

// Preload whole A operand (4 rows dup'd 4x in the 16-row slot) for all 16
// k-steps: 16 x ds_read_b64.
__device__ __forceinline__ void load_areg(const uint8_t* Els, int lane, long* areg) {
    const uint8_t* ap = Els + (lane & 3) * ELS_B + ((lane >> 4) & 3) * 8;
#pragma unroll
    for (int t = 0; t < 16; ++t)
        areg[t] = *reinterpret_cast<const long*>(ap + t * 32);
}

// Issue the first 8 k-steps of a layer's B stream (kept in flight across the
// following barrier / LN — this is the latency-hiding hoist).
template <int NSUB>
__device__ __forceinline__ void prefetchB(const uint8_t* __restrict__ bp,
                                          int s0, long bb[8][4]) {
#pragma unroll
    for (int p = 0; p < 8; ++p)
#pragma unroll
        for (int s = 0; s < NSUB; ++s)
            bb[p][s] = *reinterpret_cast<const long*>(bp + ((s0 + s) * 16 + p) * 512);
}

// C[16(dup rows) x NSUB*16 cols] over K=512, fp8 MFMA, consuming the
// prefetched pipe and rolling it forward (depth 8).
template <int NSUB>
__device__ __forceinline__ void gemm_body(const uint8_t* __restrict__ bp,
                                          int s0, const long* areg,
                                          long bb[8][4], v4f* acc) {
#pragma unroll
    for (int s = 0; s < NSUB; ++s) acc[s] = (v4f){0.f, 0.f, 0.f, 0.f};
#pragma unroll
    for (int t = 0; t < 16; ++t) {
        long a = areg[t];
        long bcur[NSUB];
#pragma unroll
        for (int s = 0; s < NSUB; ++s) bcur[s] = bb[t & 7][s];
        if (t < 8) {
#pragma unroll
            for (int s = 0; s < NSUB; ++s)
                bb[t & 7][s] =
                    *reinterpret_cast<const long*>(bp + ((s0 + s) * 16 + t + 8) * 512);
        }
#pragma unroll
        for (int s = 0; s < NSUB; ++s)
            acc[s] = __builtin_amdgcn_mfma_f32_16x16x32_fp8_fp8(a, bcur[s],
                                                                acc[s], 0, 0, 0);
    }
}

// Tropical-LN on one row (1 wave, lane-major): exact order stats via
// in-register bitonic; relu; subtract rowmax; 64*exp -> fp8 into Els.
__device__ __forceinline__ void ln_row(const float* hbuf,
                                       const float* __restrict__ lw,
                                       const float* __restrict__ lb,
                                       uint8_t* Els, float* crow,
                                       int w, int lane) {
    // lw/lb loads issued FIRST so they're in flight during the whole sort.
    const float4* lw4 = reinterpret_cast<const float4*>(lw + lane * 8);
    const float4* lb4 = reinterpret_cast<const float4*>(lb + lane * 8);
    float4 wa = lw4[0], wb = lw4[1], ba = lb4[0], bbv = lb4[1];

    float h[8], v[8];
    {
        const float* hp = hbuf + w * 512 + lane * 8;
        float4 a = *reinterpret_cast<const float4*>(hp);
        float4 b = *reinterpret_cast<const float4*>(hp + 4);
        h[0] = a.x; h[1] = a.y; h[2] = a.z; h[3] = a.w;
        h[4] = b.x; h[5] = b.y; h[6] = b.z; h[7] = b.w;
#pragma unroll
        for (int j = 0; j < 8; ++j) v[j] = h[j];
    }
    // Bitonic sort of 512 values, element e = lane*8 + j, ascending.
#pragma unroll
    for (int k = 2; k <= 512; k <<= 1) {
#pragma unroll
        for (int jj = 256; jj > 0; jj >>= 1) {
            if (jj >= k) continue;
            if (jj >= 8) {
                int lm = jj >> 3;
#pragma unroll
                for (int j = 0; j < 8; ++j) {
                    float pv = __shfl_xor(v[j], lm);
                    bool up = ((((lane << 3) | j) & k) == 0);
                    bool low = ((lane & lm) == 0);
                    v[j] = (up == low) ? fminf(v[j], pv) : fmaxf(v[j], pv);
                }
            } else {
#pragma unroll
                for (int j = 0; j < 8; ++j) {
                    if (j & jj) continue;
                    int jh = j | jj;
                    bool up = ((((lane << 3) | j) & k) == 0);
                    float a = v[j], c = v[jh];
                    float lo = fminf(a, c), hi = fmaxf(a, c);
                    v[j] = up ? lo : hi;
                    v[jh] = up ? hi : lo;
                }
            }
        }
    }
    float s127 = __shfl(v[7], 15);
    float s128 = __shfl(v[0], 16);
    float med  = __shfl(v[7], 31);
    float s383 = __shfl(v[7], 47);
    float s384 = __shfl(v[0], 48);
    float q25 = s127 + 0.75f * (s128 - s127);
    float q75 = s383 + 0.25f * (s384 - s383);
    float inv = 1.0f / fmaxf(q75 - q25, 1e-6f);

    float y[8], cm = 0.0f;                      // y >= 0 after relu
    {
        float lwv[8] = {wa.x, wa.y, wa.z, wa.w, wb.x, wb.y, wb.z, wb.w};
        float lbv[8] = {ba.x, ba.y, ba.z, ba.w, bbv.x, bbv.y, bbv.z, bbv.w};
#pragma unroll
        for (int j = 0; j < 8; ++j) {
            y[j] = fmaxf((h[j] - med) * inv * lwv[j] + lbv[j], 0.0f);
            cm = fmaxf(cm, y[j]);
        }
    }
#pragma unroll
    for (int s = 32; s > 0; s >>= 1) cm = fmaxf(cm, __shfl_xor(cm, s));
    {
        float e[8];
#pragma unroll
        for (int j = 0; j < 8; ++j) e[j] = 64.0f * __expf(y[j] - cm);
        int2 o;
        o.x = pk4_fp8(e[0], e[1], e[2], e[3]);
        o.y = pk4_fp8(e[4], e[5], e[6], e[7]);
        *reinterpret_cast<int2*>(&Els[w * ELS_B + lane * 8]) = o;
    }
    if (lane == 0) crow[w] = cm;
}

__global__ __launch_bounds__(512, 2) void fused_rows(
    const float* __restrict__ x,
    const float* __restrict__ b1,
    const float* __restrict__ ln1w, const float* __restrict__ ln1b,
    const float* __restrict__ b2,
    const float* __restrict__ ln2w, const float* __restrict__ ln2b,
    const float* __restrict__ b3,
    const uint8_t* __restrict__ Ew,
    float* __restrict__ out)
{
    __shared__ uint8_t Els[4 * ELS_B];         // fp8 activations
    __shared__ float hbuf[4 * 512];            // pre-LN layer output
    __shared__ float crow[4];                  // per-row shift (last LN)

    const int tid = threadIdx.x;
    const int lane = tid & 63;
    const int w = tid >> 6;                    // wave id 0..7
    const int r = lane & 15, q = lane >> 4;
    const int blk = blockIdx.x;                // rows 4*blk .. 4*blk+3

    const uint8_t* bp1 = Ew + lane * 8;
    const uint8_t* bp2 = bp1 + 262144;
    const uint8_t* bp3 = bp1 + 524288;

    long bb[8][4];
    long areg[16];
    v4f acc[4];

    // ---- layer-1 B prefetch in flight during the exp(x) prologue ----
    prefetchB<4>(bp1, w * 4, bb);

    // ---- phase 0: A1 = fp8(4*exp(x)) for this block's 4 rows ----
    // (+ln4 shift cancels in LN1's median subtraction; keeps fp8 normal-range)
    {
        int row = tid >> 7, col = (tid & 127) * 4;
        float4 a = *reinterpret_cast<const float4*>(x + blk * 2048 + row * 512 + col);
        *reinterpret_cast<int*>(&Els[row * ELS_B + col]) =
            pk4_fp8(4.0f * __expf(a.x), 4.0f * __expf(a.y),
                    4.0f * __expf(a.z), 4.0f * __expf(a.w));
    }
    __syncthreads();

    // ===== layer 1: wave w covers cols w*64..w*64+64 (tiles w*4..w*4+4) =====
    load_areg(Els, lane, areg);
    gemm_body<4>(bp1, w * 4, areg, bb, acc);
    if (q == 0) {
#pragma unroll
        for (int s = 0; s < 4; ++s) {
            int col = (w * 4 + s) * 16 + r;
            float bbv = b1[col];
#pragma unroll
            for (int t = 0; t < 4; ++t)
                hbuf[t * 512 + col] = __logf(acc[s][t]) + bbv;
        }
    }
    prefetchB<4>(bp2, w * 4, bb);              // layer-2 B rides over LN1
    __syncthreads();
    if (w < 4) ln_row(hbuf, ln1w, ln1b, Els, crow, w, lane);
    __syncthreads();

    // ===== layer 2 (uniform ln64 - cm1 shift absorbed by LN2's median) =====
    load_areg(Els, lane, areg);
    gemm_body<4>(bp2, w * 4, areg, bb, acc);
    if (q == 0) {
#pragma unroll
        for (int s = 0; s < 4; ++s) {
            int col = (w * 4 + s) * 16 + r;
            float bbv = b2[col];
#pragma unroll
            for (int t = 0; t < 4; ++t)
                hbuf[t * 512 + col] = __logf(acc[s][t]) + bbv;
        }
    }
    prefetchB<2>(bp3, w * 2, bb);              // layer-3 B rides over LN2
    __syncthreads();
    if (w < 4) ln_row(hbuf, ln2w, ln2b, Els, crow, w, lane);
    __syncthreads();

    // ===== layer 3 (N=256, tiles w*2..w*2+2): out = log(acc)+cm2-ln64+b3 =====
    load_areg(Els, lane, areg);
    gemm_body<2>(bp3, w * 2, areg, bb, acc);
    if (q == 0) {
#pragma unroll
        for (int s = 0; s < 2; ++s) {
            int col = (w * 2 + s) * 16 + r;
            float bbv = b3[col] - LN64f;
#pragma unroll
            for (int t = 0; t < 4; ++t)
                out[(blk * 4 + t) * 256 + col] = __logf(acc[s][t]) + crow[t] + bbv;
        }
    }
}

extern "C" void kernel_launch(void* const* d_in, const int* in_sizes, int n_in,
                              void* d_out, int out_size, void* d_ws, size_t ws_size,
                              hipStream_t stream) {
    const float* x    = (const float*)d_in[0];
    const float* w1   = (const float*)d_in[1];
    const float* b1   = (const float*)d_in[2];
    const float* ln1w = (const float*)d_in[3];
    const float* ln1b = (const float*)d_in[4];
    const float* w2   = (const float*)d_in[5];
    const float* b2   = (const float*)d_in[6];
    const float* ln2w = (const float*)d_in[7];
    const float* ln2b = (const float*)d_in[8];
    const float* w3   = (const float*)d_in[9];
    const float* b3   = (const float*)d_in[10];
    float* out = (float*)d_out;

    uint8_t* Ew = (uint8_t*)d_ws;              // 655360 B fp8 = 640 KB

    expW_frag<<<320, 256, 0, stream>>>(w1, w2, w3, Ew);
    fused_rows<<<256, 512, 0, stream>>>(x, b1, ln1w, ln1b, b2, ln2w, ln2b,
                                        b3, Ew, out);
}